// Round 8
// baseline (465.707 us; speedup 1.0000x reference)
//
#include <hip/hip_runtime.h>
#include <stdint.h>

#define B_ 8
#define T_ 4096
#define D_ 1024
#define H_ 1024
#define M_ (B_*T_)   /* 32768 */
#define K_ D_
#define N_ H_
#define TC 32
#define NC (T_/TC)   /* 128 */

typedef short short8 __attribute__((ext_vector_type(8)));
typedef float f32x4 __attribute__((ext_vector_type(4)));
typedef unsigned short ushort8v __attribute__((ext_vector_type(8)));

__device__ __forceinline__ float bf2f(unsigned short u) {
    union { unsigned int i; float f; } x; x.i = ((unsigned int)u) << 16; return x.f;
}
__device__ __forceinline__ unsigned short f2bf(float f) {
    union { float f; unsigned int i; } x; x.f = f;
    unsigned int u = x.i;
    unsigned int r = u + 0x7fffu + ((u >> 16) & 1u);
    return (unsigned short)(r >> 16);
}
__device__ __forceinline__ void gld_lds16(const unsigned short* g, unsigned short* l) {
    __builtin_amdgcn_global_load_lds(
        (const __attribute__((address_space(1))) void*)(const void*)g,
        (__attribute__((address_space(3))) void*)(void*)l, 16, 0, 0);
}
// sigmoid/gfun via raw v_rcp_f32 (1 instr) instead of IEEE divide chain.
__device__ __forceinline__ float sigm_neg(float k) {   // 1/(1+exp(k)) = 1 - sigmoid(k)
    return __builtin_amdgcn_rcpf(1.f + __expf(k));
}
__device__ __forceinline__ float gfun(float x) {       // x>=0: x+0.5 ; x<0: sigmoid(x)
    float neg = __builtin_amdgcn_rcpf(1.f + __expf(-x));
    return x >= 0.f ? x + 0.5f : neg;
}

// ---------------- fp32 -> bf16 convert ----------------
__global__ void cvt_kernel(const float* __restrict__ src, unsigned short* __restrict__ dst, int n4) {
    int i = blockIdx.x * blockDim.x + threadIdx.x;
    const int stride = gridDim.x * blockDim.x;
    for (; i < n4; i += stride) {
        float4 v = ((const float4*)src)[i];
        ushort4 o;
        o.x = f2bf(v.x); o.y = f2bf(v.y); o.z = f2bf(v.z); o.w = f2bf(v.w);
        ((ushort4*)dst)[i] = o;
    }
}

// both weight matrices in one launch (blockIdx.y selects)
__global__ void cvtw_kernel(const float* __restrict__ Wz, const float* __restrict__ Wh,
                            unsigned short* __restrict__ wzb, unsigned short* __restrict__ whb, int n4) {
    const float* src = blockIdx.y ? Wh : Wz;
    unsigned short* dst = blockIdx.y ? whb : wzb;
    int i = blockIdx.x * blockDim.x + threadIdx.x;
    const int stride = gridDim.x * blockDim.x;
    for (; i < n4; i += stride) {
        float4 v = ((const float4*)src)[i];
        ushort4 o;
        o.x = f2bf(v.x); o.y = f2bf(v.y); o.z = f2bf(v.z); o.w = f2bf(v.w);
        ((ushort4*)dst)[i] = o;
    }
}

// ---------------- bf16 MFMA GEMM: 256x256 tile, 8-phase, persistent, READ-PIPELINED ------
// vs R2 steady state (141 us, MfmaUtil 41%): ds_reads for each QUAD are issued inside the
// PREVIOUS phase's MFMA window (after that phase's opening barrier), so the ~4600 cyc/iter
// of LDS-read drain overlaps the ~4966 cyc of MFMA instead of alternating with it.
// Register plan (fixes R3's spill: 128 acc + 96 frag + addr > 256 -> scratch):
//   Ar2[4][2] = A rows m0-3 of wave tile; Ar[4][2] = m4-7; Br[4][2] shared.
//   128 acc + 64 frag + ~35 addr ~= 227 <= 256. TRIPWIRE: WRITE_SIZE must stay 131072 KB.
// Rotation (operands of every QUAD read >=1 phase earlier; hazards verified):
//   P1 rd Br23<-s0 | Q(Ar2,0,0)      P5 rd Br23<-s1 | Q(Ar2,0,0)
//   P2 rd Ar<-s0m47| Q(Ar2,0,2)      P6 rd Ar<-s1m47| Q(Ar2,0,2)
//   P3 (none)      | Q(Ar,4,0)       P7 (none)      | Q(Ar,4,0)
//   P4 vm4; rd Ar2,Br01<-s1 | Q(Ar,4,2)   P8 vm4; rd Ar2,Br01<-s0 | Q(Ar,4,2)
#define SB() __builtin_amdgcn_sched_barrier(0)
#define BAR() do { SB(); __builtin_amdgcn_s_barrier(); SB(); } while (0)

__global__ __launch_bounds__(512, 2) void gemm_kernel(
    const unsigned short* __restrict__ Xb,
    const unsigned short* __restrict__ Wzb,
    const unsigned short* __restrict__ Whb,
    const float* __restrict__ bz, const float* __restrict__ bh,
    unsigned short* __restrict__ KzOut, unsigned short* __restrict__ KhOut)
{
    __shared__ __align__(16) unsigned short ldsA[2][256 * 64];
    __shared__ __align__(16) unsigned short ldsB[2][256 * 64];

    const int bx = blockIdx.x;      // row-supertile: rows [bx*1024, bx*1024+1024)
    const int bn = blockIdx.y;
    const int mat = blockIdx.z;
    const unsigned short* Wb = mat ? Whb : Wzb;
    const float* bias = mat ? bh : bz;
    unsigned short* Out = mat ? KhOut : KzOut;

    const int tid = threadIdx.x;
    const int w = tid >> 6, lane = tid & 63;
    const int wm = w >> 2, wn = w & 3;       // 2 x 4 wave grid; wave owns 128x64 of C

    // ---- staging addressing (inverse-swizzled global source) ----
    const int srow = lane >> 3;                       // row within 8-row wave group
    const int schunk = ((lane & 7) ^ srow) << 3;      // ushort offset of 16B chunk
    const unsigned short* gA = Xb + (size_t)(bx * 1024 + srow) * K_ + schunk;
    const unsigned short* gB = Wb + (size_t)(bn * 256 + srow) * K_ + schunk;

// global K-step g: A row-block = (g>>4)*256 within the supertile, kt = g&15
#define STAGE_A(s, g, h) do { \
    gld_lds16(gA + (size_t)(((g) >> 4) * 256 + (h)*128 + w*8) * K_ + ((g)&15) * 64, \
              &ldsA[s][((h)*128 + w*8) * 64]); \
    gld_lds16(gA + (size_t)(((g) >> 4) * 256 + (h)*128 + 64 + w*8) * K_ + ((g)&15) * 64, \
              &ldsA[s][((h)*128 + 64 + w*8) * 64]); \
  } while (0)
#define STAGE_B(s, g, h) do { \
    gld_lds16(gB + (size_t)((h)*128 + w*8) * K_ + ((g)&15) * 64, \
              &ldsB[s][((h)*128 + w*8) * 64]); \
    gld_lds16(gB + (size_t)((h)*128 + 64 + w*8) * K_ + ((g)&15) * 64, \
              &ldsB[s][((h)*128 + 64 + w*8) * 64]); \
  } while (0)

    // ---- fragment read addressing (swizzled) ----
    const int lrow = lane & 15;
    const int q = lane >> 4;
    const int sw0 = (q ^ (lane & 7)) << 3;   // ushort offset of kh=0 slot; kh=1 is ^32

#define LDA(s, fm, kh) (*(const short8*)&ldsA[s][(wm*128 + (fm)*16 + lrow) * 64 + (sw0 ^ ((kh)*32))])
#define LDB(s, fn, kh) (*(const short8*)&ldsB[s][(wn*64  + (fn)*16 + lrow) * 64 + (sw0 ^ ((kh)*32))])

#define RD_A4(DST, s, fmb) do { \
    _Pragma("unroll") for (int f = 0; f < 4; ++f) { DST[f][0] = LDA(s, (fmb)+f, 0); DST[f][1] = LDA(s, (fmb)+f, 1); } \
  } while (0)
#define RD_B2(s, fnb) do { \
    _Pragma("unroll") for (int g2_ = 0; g2_ < 2; ++g2_) { Br[(fnb)+g2_][0] = LDB(s, (fnb)+g2_, 0); Br[(fnb)+g2_][1] = LDB(s, (fnb)+g2_, 1); } \
  } while (0)

#define QUAD(AF, mb, nb) do { \
    __builtin_amdgcn_s_setprio(1); \
    _Pragma("unroll") for (int f = 0; f < 4; ++f) { \
      _Pragma("unroll") for (int g2_ = 0; g2_ < 2; ++g2_) { \
        acc[(mb)+f][(nb)+g2_] = __builtin_amdgcn_mfma_f32_16x16x32_bf16(AF[f][0], Br[(nb)+g2_][0], acc[(mb)+f][(nb)+g2_], 0, 0, 0); \
        acc[(mb)+f][(nb)+g2_] = __builtin_amdgcn_mfma_f32_16x16x32_bf16(AF[f][1], Br[(nb)+g2_][1], acc[(mb)+f][(nb)+g2_], 0, 0, 0); \
      } \
    } \
    __builtin_amdgcn_s_setprio(0); \
  } while (0)

    f32x4 acc[8][4];
    short8 Ar[4][2], Ar2[4][2], Br[4][2];

    // bias values are t-invariant; hoist
    float bb[4];
#pragma unroll
    for (int fn = 0; fn < 4; ++fn) bb[fn] = bias[bn * 256 + wn * 64 + fn * 16 + lrow];

    // ---- prologue: g=0 (slot0, A+B all halves) + g=1 B halves; prime P1 operands ----
    STAGE_B(0, 0, 0); STAGE_B(0, 0, 1);
    STAGE_A(0, 0, 0); STAGE_A(0, 0, 1);
    STAGE_B(1, 1, 0); STAGE_B(1, 1, 1);
    SB();
    asm volatile("s_waitcnt vmcnt(4)" ::: "memory");   // g=0 landed; g=1 B in flight
    BAR();
    RD_A4(Ar2, 0, 0); RD_B2(0, 0);   // prime: P1's operands (slot0 g0)

#pragma unroll 1
    for (int t = 0; t < 4; ++t) {
#pragma unroll
        for (int i = 0; i < 8; ++i)
#pragma unroll
            for (int j = 0; j < 4; ++j) acc[i][j] = (f32x4){0.f, 0.f, 0.f, 0.f};

#pragma unroll 1
        for (int i = 0; i < 8; ++i) {
            const int g1 = t * 16 + 2 * i + 1;
            const int g2 = g1 + 1;
            const int g3 = g1 + 2;
            const bool st = (g2 < 64);   // false only at t=3,i=7

            // ---- P1: stage s1 A-h0(g1); rd Br23<-s0; Q(Ar2,0,0) [ops read prev-P8] ----
            STAGE_A(1, g1, 0);
            BAR();
            RD_B2(0, 2);
            SB();
            QUAD(Ar2, 0, 0);
            BAR();
            // ---- P2: stage s1 A-h1(g1); rd Ar<-s0 m4-7; Q(Ar2,0,2) ----
            STAGE_A(1, g1, 1);
            BAR();
            RD_A4(Ar, 0, 4);
            SB();
            QUAD(Ar2, 0, 2);
            BAR();
            // ---- P3: stage s0 B-h0(g2); Q(Ar,4,0) ----
            if (st) STAGE_B(0, g2, 0);
            BAR();
            QUAD(Ar, 4, 0);
            BAR();
            // ---- P4: stage s0 B-h1(g2); GATE g1 landed; rd Ar2,Br01<-s1; Q(Ar,4,2) ----
            if (st) {
                STAGE_B(0, g2, 1);
                SB();
                asm volatile("s_waitcnt vmcnt(4)" ::: "memory");
            } else {
                asm volatile("s_waitcnt vmcnt(0)" ::: "memory");   // final drain
            }
            BAR();
            RD_A4(Ar2, 1, 0); RD_B2(1, 0);
            SB();
            QUAD(Ar, 4, 2);
            BAR();
            // ---- P5: stage s0 A-h0(g2); rd Br23<-s1; Q(Ar2,0,0) ----
            if (st) STAGE_A(0, g2, 0);
            BAR();
            RD_B2(1, 2);
            SB();
            QUAD(Ar2, 0, 0);
            BAR();
            // ---- P6: stage s0 A-h1(g2); rd Ar<-s1 m4-7; Q(Ar2,0,2) ----
            if (st) STAGE_A(0, g2, 1);
            BAR();
            RD_A4(Ar, 1, 4);
            SB();
            QUAD(Ar2, 0, 2);
            BAR();
            // ---- P7: stage s1 B-h0(g3); Q(Ar,4,0) ----
            if (st) STAGE_B(1, g3, 0);
            BAR();
            QUAD(Ar, 4, 0);
            BAR();
            // ---- P8: stage s1 B-h1(g3); GATE g2(s0) landed; rd next-P1 ops; Q(Ar,4,2) ----
            if (st) {
                STAGE_B(1, g3, 1);
                SB();
                asm volatile("s_waitcnt vmcnt(4)" ::: "memory");
            }
            BAR();
            if (st) { RD_A4(Ar2, 0, 0); RD_B2(0, 0); SB(); }
            QUAD(Ar, 4, 2);
            BAR();
        }

        // ---- per-tile epilogue (no LDS; runs under in-flight prefetch) ----
        // K[m][n] at ((m>>2)*N + n)*4 + (m&3); m = (bx*4+t)*256 + wm*128 + fm*16 + q*4 + r
#pragma unroll
        for (int fn = 0; fn < 4; ++fn) {
            const int n = bn * 256 + wn * 64 + fn * 16 + lrow;
#pragma unroll
            for (int fm = 0; fm < 8; ++fm) {
                const int mq = (bx * 4 + t) * 64 + wm * 32 + fm * 4 + q;
                ushort4 o;
                o.x = f2bf(acc[fm][fn][0] + bb[fn]);
                o.y = f2bf(acc[fm][fn][1] + bb[fn]);
                o.z = f2bf(acc[fm][fn][2] + bb[fn]);
                o.w = f2bf(acc[fm][fn][3] + bb[fn]);
                *(ushort4*)(Out + ((size_t)mq * N_ + n) * 4) = o;
            }
        }
    }
}

// Packed-layout accessor note for scans:
// K[m][n] lives at ((m>>2)*N + n)*4 + (m&3), m = b*T + t.
// A thread owning columns hb..hb+3 loads, per t-quad q, two 16B vectors:
//   base = ((b*1024 + (t0>>2))*N + hb)*4 ; v0 = cols hb,hb+1 ; v1 = cols hb+2,hb+3
//   value(col j, t0+r) = v[j>>1][(j&1)*4 + r]

// per-t-quad math, shared by scanA/scanC
#define QUAD_MATH(Z0, Z1, HH0, HH1, CYSTMT)                                            \
    _Pragma("unroll")                                                                  \
    for (int r = 0; r < 4; r++) {                                                      \
        float kzf[4] = {bf2f(Z0[r]), bf2f(Z0[4 + r]), bf2f(Z1[r]), bf2f(Z1[4 + r])};   \
        float khf[4] = {bf2f(HH0[r]), bf2f(HH0[4 + r]), bf2f(HH1[r]), bf2f(HH1[4 + r])};\
        _Pragma("unroll")                                                              \
        for (int j = 0; j < 4; j++) {                                                  \
            float f = sigm_neg(kzf[j]);            /* 1 - sigmoid(kz) */               \
            float v = (1.f - f) * gfun(khf[j]);    /* sigmoid(kz)*g(kh) */             \
            CYSTMT                                                                     \
        }                                                                              \
    }

// ---------------- scan A: per-chunk affine aggregates (F = prod f, V) ----------------
// 2-deep register prefetch: 8 independent 16B loads in flight per thread
__global__ __launch_bounds__(256) void scanA_kernel(const unsigned short* __restrict__ Kz,
                                                    const unsigned short* __restrict__ Kh,
                                                    float* __restrict__ Fc, float* __restrict__ Vc)
{
    const int c = blockIdx.x, b = blockIdx.y;
    const int hb = threadIdx.x * 4;
    float F[4] = {1.f, 1.f, 1.f, 1.f}, V[4] = {0.f, 0.f, 0.f, 0.f};
    const size_t base0 = ((size_t)(b * (T_ / 4) + c * (TC / 4)) * N_ + hb) * 4;
    const size_t str = (size_t)N_ * 4;
    ushort8v cz0 = *(const ushort8v*)(Kz + base0);
    ushort8v cz1 = *(const ushort8v*)(Kz + base0 + 8);
    ushort8v ch0 = *(const ushort8v*)(Kh + base0);
    ushort8v ch1 = *(const ushort8v*)(Kh + base0 + 8);
    ushort8v az0 = *(const ushort8v*)(Kz + base0 + str);
    ushort8v az1 = *(const ushort8v*)(Kz + base0 + str + 8);
    ushort8v ah0 = *(const ushort8v*)(Kh + base0 + str);
    ushort8v ah1 = *(const ushort8v*)(Kh + base0 + str + 8);
#pragma unroll 1
    for (int qq = 0; qq < TC / 4; qq++) {
        const int qn = (qq + 2 < TC / 4) ? qq + 2 : TC / 4 - 1;   // clamped tail (L1-hot)
        const size_t nb = base0 + (size_t)qn * str;
        ushort8v bz0 = *(const ushort8v*)(Kz + nb);
        ushort8v bz1 = *(const ushort8v*)(Kz + nb + 8);
        ushort8v bh0 = *(const ushort8v*)(Kh + nb);
        ushort8v bh1 = *(const ushort8v*)(Kh + nb + 8);
        QUAD_MATH(cz0, cz1, ch0, ch1, { V[j] = f * V[j] + v; F[j] *= f; })
        cz0 = az0; cz1 = az1; ch0 = ah0; ch1 = ah1;
        az0 = bz0; az1 = bz1; ah0 = bh0; ah1 = bh1;
    }
    size_t o = ((size_t)(b * NC + c)) * H_ + hb;
    *(float4*)(Fc + o) = make_float4(F[0], F[1], F[2], F[3]);
    *(float4*)(Vc + o) = make_float4(V[0], V[1], V[2], V[3]);
}

// ---------------- scan B: serial scan over chunk aggregates; writes t=0 row ----------------
__global__ __launch_bounds__(64) void scanB_kernel(const float* __restrict__ h0,
                                                   const float* __restrict__ Fc,
                                                   const float* __restrict__ Vc,
                                                   float* __restrict__ Carry,
                                                   float* __restrict__ Out)
{
    const int b = blockIdx.x;
    const int h = blockIdx.y * 256 + threadIdx.x * 4;
    float cy[4];
#pragma unroll
    for (int j = 0; j < 4; j++) cy[j] = gfun(h0[(size_t)b * H_ + h + j]);
    *(float4*)(Out + (size_t)b * (T_ + 1) * H_ + h) = make_float4(cy[0], cy[1], cy[2], cy[3]);
    size_t o = ((size_t)(b * NC)) * H_ + h;
    float4 F4 = *(const float4*)(Fc + o);
    float4 V4 = *(const float4*)(Vc + o);
    for (int c = 0; c < NC; c++) {
        const size_t on = o + H_;
        float4 nF, nV;
        if (c + 1 < NC) {
            nF = *(const float4*)(Fc + on);
            nV = *(const float4*)(Vc + on);
        }
        *(float4*)(Carry + o) = make_float4(cy[0], cy[1], cy[2], cy[3]);
        cy[0] = F4.x * cy[0] + V4.x;
        cy[1] = F4.y * cy[1] + V4.y;
        cy[2] = F4.z * cy[2] + V4.z;
        cy[3] = F4.w * cy[3] + V4.w;
        F4 = nF; V4 = nV; o = on;
    }
}

// ---------------- scan C: replay chunks with incoming carry, write outputs ----------------
__global__ __launch_bounds__(256) void scanC_kernel(const unsigned short* __restrict__ Kz,
                                                    const unsigned short* __restrict__ Kh,
                                                    const float* __restrict__ Carry,
                                                    float* __restrict__ Out)
{
    const int c = blockIdx.x, b = blockIdx.y;
    const int hb = threadIdx.x * 4;
    float cy[4];
    {
        float4 c4 = *(const float4*)(Carry + ((size_t)(b * NC + c)) * H_ + hb);
        cy[0] = c4.x; cy[1] = c4.y; cy[2] = c4.z; cy[3] = c4.w;
    }
    const size_t base0 = ((size_t)(b * (T_ / 4) + c * (TC / 4)) * N_ + hb) * 4;
    const size_t str = (size_t)N_ * 4;
    size_t ob = ((size_t)(b * (T_ + 1) + c * TC + 1)) * H_ + hb;
    ushort8v cz0 = *(const ushort8v*)(Kz + base0);
    ushort8v cz1 = *(const ushort8v*)(Kz + base0 + 8);
    ushort8v ch0 = *(const ushort8v*)(Kh + base0);
    ushort8v ch1 = *(const ushort8v*)(Kh + base0 + 8);
    ushort8v az0 = *(const ushort8v*)(Kz + base0 + str);
    ushort8v az1 = *(const ushort8v*)(Kz + base0 + str + 8);
    ushort8v ah0 = *(const ushort8v*)(Kh + base0 + str);
    ushort8v ah1 = *(const ushort8v*)(Kh + base0 + str + 8);
#pragma unroll 1
    for (int qq = 0; qq < TC / 4; qq++) {
        const int qn = (qq + 2 < TC / 4) ? qq + 2 : TC / 4 - 1;
        const size_t nb = base0 + (size_t)qn * str;
        ushort8v bz0 = *(const ushort8v*)(Kz + nb);
        ushort8v bz1 = *(const ushort8v*)(Kz + nb + 8);
        ushort8v bh0 = *(const ushort8v*)(Kh + nb);
        ushort8v bh1 = *(const ushort8v*)(Kh + nb + 8);
        QUAD_MATH(cz0, cz1, ch0, ch1, {
            cy[j] = f * cy[j] + v;
            if (j == 3) { *(float4*)(Out + ob) = make_float4(cy[0], cy[1], cy[2], cy[3]); ob += H_; }
        })
        cz0 = az0; cz1 = az1; ch0 = ah0; ch1 = ah1;
        az0 = bz0; az1 = bz1; ah0 = bh0; ah1 = bh1;
    }
}

extern "C" void kernel_launch(void* const* d_in, const int* in_sizes, int n_in,
                              void* d_out, int out_size, void* d_ws, size_t ws_size,
                              hipStream_t stream)
{
    const float* x  = (const float*)d_in[0];
    const float* h0 = (const float*)d_in[1];
    const float* Wz = (const float*)d_in[2];
    const float* bz = (const float*)d_in[3];
    const float* Wh = (const float*)d_in[4];
    const float* bh = (const float*)d_in[5];
    float* out = (float*)d_out;

    char* ws = (char*)d_ws;
    unsigned short* xb  = (unsigned short*)ws; ws += (size_t)M_ * K_ * 2;   // 64 MiB
    unsigned short* wzb = (unsigned short*)ws; ws += (size_t)N_ * K_ * 2;   // 2 MiB
    unsigned short* whb = (unsigned short*)ws; ws += (size_t)N_ * K_ * 2;   // 2 MiB
    unsigned short* kz  = (unsigned short*)ws; ws += (size_t)M_ * N_ * 2;   // 64 MiB
    unsigned short* kh  = (unsigned short*)ws; ws += (size_t)M_ * N_ * 2;   // 64 MiB
    float* Fc    = (float*)ws; ws += (size_t)B_ * NC * H_ * 4;              // 4 MiB
    float* Vc    = (float*)ws; ws += (size_t)B_ * NC * H_ * 4;              // 4 MiB
    float* Carry = (float*)ws; ws += (size_t)B_ * NC * H_ * 4;              // 4 MiB

    cvt_kernel<<<2048, 256, 0, stream>>>(x, xb, M_ * K_ / 4);
    cvtw_kernel<<<dim3(128, 2), 256, 0, stream>>>(Wz, Wh, wzb, whb, N_ * K_ / 4);

    dim3 gg(M_ / 1024, N_ / 256, 2);
    gemm_kernel<<<gg, 512, 0, stream>>>(xb, wzb, whb, bz, bh, kz, kh);

    scanA_kernel<<<dim3(NC, B_), 256, 0, stream>>>(kz, kh, Fc, Vc);
    scanB_kernel<<<dim3(B_, H_ / 256), 64, 0, stream>>>(h0, Fc, Vc, Carry, out);
    scanC_kernel<<<dim3(NC, B_), 256, 0, stream>>>(kz, kh, Carry, out);
}

// Round 9
// 456.720 us; speedup vs baseline: 1.0197x; 1.0197x over previous
//
#include <hip/hip_runtime.h>
#include <stdint.h>

#define B_ 8
#define T_ 4096
#define D_ 1024
#define H_ 1024
#define M_ (B_*T_)   /* 32768 */
#define K_ D_
#define N_ H_
#define TC 16
#define NC (T_/TC)   /* 256 */

typedef short short8 __attribute__((ext_vector_type(8)));
typedef float f32x4 __attribute__((ext_vector_type(4)));
typedef unsigned short ushort8v __attribute__((ext_vector_type(8)));

__device__ __forceinline__ float bf2f(unsigned short u) {
    union { unsigned int i; float f; } x; x.i = ((unsigned int)u) << 16; return x.f;
}
__device__ __forceinline__ unsigned short f2bf(float f) {
    union { float f; unsigned int i; } x; x.f = f;
    unsigned int u = x.i;
    unsigned int r = u + 0x7fffu + ((u >> 16) & 1u);
    return (unsigned short)(r >> 16);
}
__device__ __forceinline__ void gld_lds16(const unsigned short* g, unsigned short* l) {
    __builtin_amdgcn_global_load_lds(
        (const __attribute__((address_space(1))) void*)(const void*)g,
        (__attribute__((address_space(3))) void*)(void*)l, 16, 0, 0);
}
// sigmoid/gfun via raw v_rcp_f32 (1 instr) instead of IEEE divide chain.
__device__ __forceinline__ float sigm_neg(float k) {   // 1/(1+exp(k)) = 1 - sigmoid(k)
    return __builtin_amdgcn_rcpf(1.f + __expf(k));
}
__device__ __forceinline__ float gfun(float x) {       // x>=0: x+0.5 ; x<0: sigmoid(x)
    float neg = __builtin_amdgcn_rcpf(1.f + __expf(-x));
    return x >= 0.f ? x + 0.5f : neg;
}

// ---------------- fp32 -> bf16 convert ----------------
__global__ void cvt_kernel(const float* __restrict__ src, unsigned short* __restrict__ dst, int n4) {
    int i = blockIdx.x * blockDim.x + threadIdx.x;
    const int stride = gridDim.x * blockDim.x;
    for (; i < n4; i += stride) {
        float4 v = ((const float4*)src)[i];
        ushort4 o;
        o.x = f2bf(v.x); o.y = f2bf(v.y); o.z = f2bf(v.z); o.w = f2bf(v.w);
        ((ushort4*)dst)[i] = o;
    }
}

// both weight matrices in one launch (blockIdx.y selects)
__global__ void cvtw_kernel(const float* __restrict__ Wz, const float* __restrict__ Wh,
                            unsigned short* __restrict__ wzb, unsigned short* __restrict__ whb, int n4) {
    const float* src = blockIdx.y ? Wh : Wz;
    unsigned short* dst = blockIdx.y ? whb : wzb;
    int i = blockIdx.x * blockDim.x + threadIdx.x;
    const int stride = gridDim.x * blockDim.x;
    for (; i < n4; i += stride) {
        float4 v = ((const float4*)src)[i];
        ushort4 o;
        o.x = f2bf(v.x); o.y = f2bf(v.y); o.z = f2bf(v.z); o.w = f2bf(v.w);
        ((ushort4*)dst)[i] = o;
    }
}

// ---------------- bf16 MFMA GEMM: 256x256 tile, 8-phase, persistent (R2/R5 steady state) --
// PARKED at 141 us / MfmaUtil 41%. The 128-AGPR accumulator leaves only 128 VGPRs at
// 8-wave residency (unified file, 256/wave), so the read-ahead pipeline cannot fit:
// R3 and R8 both spilled (WRITE_SIZE tripwire). Do not re-attempt without shrinking acc.
#define SB() __builtin_amdgcn_sched_barrier(0)
#define BAR() do { SB(); __builtin_amdgcn_s_barrier(); SB(); } while (0)

__global__ __launch_bounds__(512, 2) void gemm_kernel(
    const unsigned short* __restrict__ Xb,
    const unsigned short* __restrict__ Wzb,
    const unsigned short* __restrict__ Whb,
    const float* __restrict__ bz, const float* __restrict__ bh,
    unsigned short* __restrict__ KzOut, unsigned short* __restrict__ KhOut)
{
    __shared__ __align__(16) unsigned short ldsA[2][256 * 64];
    __shared__ __align__(16) unsigned short ldsB[2][256 * 64];

    const int bx = blockIdx.x;      // row-supertile: rows [bx*1024, bx*1024+1024)
    const int bn = blockIdx.y;
    const int mat = blockIdx.z;
    const unsigned short* Wb = mat ? Whb : Wzb;
    const float* bias = mat ? bh : bz;
    unsigned short* Out = mat ? KhOut : KzOut;

    const int tid = threadIdx.x;
    const int w = tid >> 6, lane = tid & 63;
    const int wm = w >> 2, wn = w & 3;       // 2 x 4 wave grid; wave owns 128x64 of C

    // ---- staging addressing (inverse-swizzled global source) ----
    const int srow = lane >> 3;                       // row within 8-row wave group
    const int schunk = ((lane & 7) ^ srow) << 3;      // ushort offset of 16B chunk
    const unsigned short* gA = Xb + (size_t)(bx * 1024 + srow) * K_ + schunk;
    const unsigned short* gB = Wb + (size_t)(bn * 256 + srow) * K_ + schunk;

// global K-step g: A row-block = (g>>4)*256 within the supertile, kt = g&15
#define STAGE_A(s, g, h) do { \
    gld_lds16(gA + (size_t)(((g) >> 4) * 256 + (h)*128 + w*8) * K_ + ((g)&15) * 64, \
              &ldsA[s][((h)*128 + w*8) * 64]); \
    gld_lds16(gA + (size_t)(((g) >> 4) * 256 + (h)*128 + 64 + w*8) * K_ + ((g)&15) * 64, \
              &ldsA[s][((h)*128 + 64 + w*8) * 64]); \
  } while (0)
#define STAGE_B(s, g, h) do { \
    gld_lds16(gB + (size_t)((h)*128 + w*8) * K_ + ((g)&15) * 64, \
              &ldsB[s][((h)*128 + w*8) * 64]); \
    gld_lds16(gB + (size_t)((h)*128 + 64 + w*8) * K_ + ((g)&15) * 64, \
              &ldsB[s][((h)*128 + 64 + w*8) * 64]); \
  } while (0)

    // ---- fragment read addressing (swizzled) ----
    const int lrow = lane & 15;
    const int q = lane >> 4;
    const int sw0 = (q ^ (lane & 7)) << 3;   // ushort offset of kh=0 slot; kh=1 is ^32

#define LDA(s, fm, kh) (*(const short8*)&ldsA[s][(wm*128 + (fm)*16 + lrow) * 64 + (sw0 ^ ((kh)*32))])
#define LDB(s, fn, kh) (*(const short8*)&ldsB[s][(wn*64  + (fn)*16 + lrow) * 64 + (sw0 ^ ((kh)*32))])

#define RD_A4(s, fmb) do { \
    _Pragma("unroll") for (int f = 0; f < 4; ++f) { Ar[f][0] = LDA(s, (fmb)+f, 0); Ar[f][1] = LDA(s, (fmb)+f, 1); } \
  } while (0)
#define RD_B2(s, fnb) do { \
    _Pragma("unroll") for (int g2_ = 0; g2_ < 2; ++g2_) { Br[(fnb)+g2_][0] = LDB(s, (fnb)+g2_, 0); Br[(fnb)+g2_][1] = LDB(s, (fnb)+g2_, 1); } \
  } while (0)

#define QUAD(mb, nb) do { \
    __builtin_amdgcn_s_setprio(1); \
    _Pragma("unroll") for (int f = 0; f < 4; ++f) { \
      _Pragma("unroll") for (int g2_ = 0; g2_ < 2; ++g2_) { \
        acc[(mb)+f][(nb)+g2_] = __builtin_amdgcn_mfma_f32_16x16x32_bf16(Ar[f][0], Br[(nb)+g2_][0], acc[(mb)+f][(nb)+g2_], 0, 0, 0); \
        acc[(mb)+f][(nb)+g2_] = __builtin_amdgcn_mfma_f32_16x16x32_bf16(Ar[f][1], Br[(nb)+g2_][1], acc[(mb)+f][(nb)+g2_], 0, 0, 0); \
      } \
    } \
    __builtin_amdgcn_s_setprio(0); \
  } while (0)

    f32x4 acc[8][4];
    short8 Ar[4][2], Br[4][2];

    // bias values are t-invariant; hoist
    float bb[4];
#pragma unroll
    for (int fn = 0; fn < 4; ++fn) bb[fn] = bias[bn * 256 + wn * 64 + fn * 16 + lrow];

    // ---- prologue: g=0 (slot0, A+B all halves) + g=1 B halves ----
    STAGE_B(0, 0, 0); STAGE_B(0, 0, 1);
    STAGE_A(0, 0, 0); STAGE_A(0, 0, 1);
    STAGE_B(1, 1, 0); STAGE_B(1, 1, 1);
    SB();
    asm volatile("s_waitcnt vmcnt(4)" ::: "memory");   // g=0 landed; g=1 B in flight
    BAR();

#pragma unroll 1
    for (int t = 0; t < 4; ++t) {
#pragma unroll
        for (int i = 0; i < 8; ++i)
#pragma unroll
            for (int j = 0; j < 4; ++j) acc[i][j] = (f32x4){0.f, 0.f, 0.f, 0.f};

#pragma unroll 1
        for (int i = 0; i < 8; ++i) {
            const int g1 = t * 16 + 2 * i + 1;
            const int g2 = g1 + 1;
            const int g3 = g1 + 2;
            const bool st = (g2 < 64);   // false only at t=3,i=7

            // ---- P1: read slot0 A(m0-3)+B(n0-1); stage slot1 A-h0 (g1) ----
            RD_A4(0, 0); RD_B2(0, 0);
            STAGE_A(1, g1, 0);
            BAR();
            QUAD(0, 0);
            BAR();
            // ---- P2: read slot0 B(n2-3); stage slot1 A-h1 (g1) ----
            RD_B2(0, 2);
            STAGE_A(1, g1, 1);
            BAR();
            QUAD(0, 2);
            BAR();
            // ---- P3: read slot0 A(m4-7); stage slot0 B-h0 (g2) ----
            RD_A4(0, 4);
            if (st) STAGE_B(0, g2, 0);
            BAR();
            QUAD(4, 0);
            BAR();
            // ---- P4: stage slot0 B-h1 (g2); GATE: g1 landed before P5 ----
            if (st) {
                STAGE_B(0, g2, 1);
                SB();
                asm volatile("s_waitcnt vmcnt(4)" ::: "memory");
            } else {
                asm volatile("s_waitcnt vmcnt(0)" ::: "memory");   // final drain
            }
            BAR();
            QUAD(4, 2);
            BAR();
            // ---- P5: read slot1 A(m0-3)+B(n0-1); stage slot0 A-h0 (g2) ----
            RD_A4(1, 0); RD_B2(1, 0);
            if (st) STAGE_A(0, g2, 0);
            BAR();
            QUAD(0, 0);
            BAR();
            // ---- P6: read slot1 B(n2-3); stage slot0 A-h1 (g2) ----
            RD_B2(1, 2);
            if (st) STAGE_A(0, g2, 1);
            BAR();
            QUAD(0, 2);
            BAR();
            // ---- P7: read slot1 A(m4-7); stage slot1 B-h0 (g3) ----
            RD_A4(1, 4);
            if (st) STAGE_B(1, g3, 0);
            BAR();
            QUAD(4, 0);
            BAR();
            // ---- P8: stage slot1 B-h1 (g3); GATE: g2 (slot0) landed before next P1 ----
            if (st) {
                STAGE_B(1, g3, 1);
                SB();
                asm volatile("s_waitcnt vmcnt(4)" ::: "memory");
            }
            BAR();
            QUAD(4, 2);
            BAR();
        }

        // ---- per-tile epilogue (no LDS, runs under in-flight prefetch) ----
        // K[m][n] at ((m>>2)*N + n)*4 + (m&3); m = (bx*4+t)*256 + wm*128 + fm*16 + q*4 + r
#pragma unroll
        for (int fn = 0; fn < 4; ++fn) {
            const int n = bn * 256 + wn * 64 + fn * 16 + lrow;
#pragma unroll
            for (int fm = 0; fm < 8; ++fm) {
                const int mq = (bx * 4 + t) * 64 + wm * 32 + fm * 4 + q;
                ushort4 o;
                o.x = f2bf(acc[fm][fn][0] + bb[fn]);
                o.y = f2bf(acc[fm][fn][1] + bb[fn]);
                o.z = f2bf(acc[fm][fn][2] + bb[fn]);
                o.w = f2bf(acc[fm][fn][3] + bb[fn]);
                *(ushort4*)(Out + ((size_t)mq * N_ + n) * 4) = o;
            }
        }
    }
}

// Packed-layout accessor note for scans:
// K[m][n] lives at ((m>>2)*N + n)*4 + (m&3), m = b*T + t.
// A thread owning columns hb..hb+3 loads, per t-quad q, two 16B vectors:
//   base = ((b*1024 + (t0>>2))*N + hb)*4 ; v0 = cols hb,hb+1 ; v1 = cols hb+2,hb+3
//   value(col j, t0+r) = v[j>>1][(j&1)*4 + r]

// per-t-quad math, shared by scanA/scanC
#define QUAD_MATH(Z0, Z1, HH0, HH1, CYSTMT)                                            \
    _Pragma("unroll")                                                                  \
    for (int r = 0; r < 4; r++) {                                                      \
        float kzf[4] = {bf2f(Z0[r]), bf2f(Z0[4 + r]), bf2f(Z1[r]), bf2f(Z1[4 + r])};   \
        float khf[4] = {bf2f(HH0[r]), bf2f(HH0[4 + r]), bf2f(HH1[r]), bf2f(HH1[4 + r])};\
        _Pragma("unroll")                                                              \
        for (int j = 0; j < 4; j++) {                                                  \
            float f = sigm_neg(kzf[j]);            /* 1 - sigmoid(kz) */               \
            float v = (1.f - f) * gfun(khf[j]);    /* sigmoid(kz)*g(kh) */             \
            CYSTMT                                                                     \
        }                                                                              \
    }

// ---------------- scan A: per-chunk affine aggregates (F = prod f, V) ----------------
// TC=16, grid 2048 blocks. ALL 16 chunk loads issued upfront (L[] fully
// constant-indexed -> registers, ~64 VGPR): zero dependent load-use chains; the
// chunk's entire HBM traffic is in flight at once.
__global__ __launch_bounds__(256) void scanA_kernel(const unsigned short* __restrict__ Kz,
                                                    const unsigned short* __restrict__ Kh,
                                                    float* __restrict__ Fc, float* __restrict__ Vc)
{
    const int c = blockIdx.x, b = blockIdx.y;
    const int hb = threadIdx.x * 4;
    const size_t base0 = ((size_t)(b * (T_ / 4) + c * (TC / 4)) * N_ + hb) * 4;
    const size_t str = (size_t)N_ * 4;

    ushort8v L[TC];   // 4 vectors per t-quad x 4 quads
#pragma unroll
    for (int qq = 0; qq < TC / 4; qq++) {
        const size_t bse = base0 + (size_t)qq * str;
        L[qq * 4 + 0] = *(const ushort8v*)(Kz + bse);
        L[qq * 4 + 1] = *(const ushort8v*)(Kz + bse + 8);
        L[qq * 4 + 2] = *(const ushort8v*)(Kh + bse);
        L[qq * 4 + 3] = *(const ushort8v*)(Kh + bse + 8);
    }

    float F[4] = {1.f, 1.f, 1.f, 1.f}, V[4] = {0.f, 0.f, 0.f, 0.f};
#pragma unroll
    for (int qq = 0; qq < TC / 4; qq++) {
        QUAD_MATH(L[qq * 4 + 0], L[qq * 4 + 1], L[qq * 4 + 2], L[qq * 4 + 3],
                  { V[j] = f * V[j] + v; F[j] *= f; })
    }
    size_t o = ((size_t)(b * NC + c)) * H_ + hb;
    *(float4*)(Fc + o) = make_float4(F[0], F[1], F[2], F[3]);
    *(float4*)(Vc + o) = make_float4(V[0], V[1], V[2], V[3]);
}

// ---------------- scan B: serial scan over chunk aggregates; writes t=0 row ----------------
// spread over (B, H/256) blocks x 64 threads; F/V prefetched one step ahead of the chain
__global__ __launch_bounds__(64) void scanB_kernel(const float* __restrict__ h0,
                                                   const float* __restrict__ Fc,
                                                   const float* __restrict__ Vc,
                                                   float* __restrict__ Carry,
                                                   float* __restrict__ Out)
{
    const int b = blockIdx.x;
    const int h = blockIdx.y * 256 + threadIdx.x * 4;
    float cy[4];
#pragma unroll
    for (int j = 0; j < 4; j++) cy[j] = gfun(h0[(size_t)b * H_ + h + j]);
    *(float4*)(Out + (size_t)b * (T_ + 1) * H_ + h) = make_float4(cy[0], cy[1], cy[2], cy[3]);
    size_t o = ((size_t)(b * NC)) * H_ + h;
    float4 F4 = *(const float4*)(Fc + o);
    float4 V4 = *(const float4*)(Vc + o);
    for (int c = 0; c < NC; c++) {
        const size_t on = o + H_;
        float4 nF, nV;
        if (c + 1 < NC) {
            nF = *(const float4*)(Fc + on);
            nV = *(const float4*)(Vc + on);
        }
        *(float4*)(Carry + o) = make_float4(cy[0], cy[1], cy[2], cy[3]);
        cy[0] = F4.x * cy[0] + V4.x;
        cy[1] = F4.y * cy[1] + V4.y;
        cy[2] = F4.z * cy[2] + V4.z;
        cy[3] = F4.w * cy[3] + V4.w;
        F4 = nF; V4 = nV; o = on;
    }
}

// ---------------- scan C: replay chunks with incoming carry, write outputs ----------------
// same upfront-load structure as scanA
__global__ __launch_bounds__(256) void scanC_kernel(const unsigned short* __restrict__ Kz,
                                                    const unsigned short* __restrict__ Kh,
                                                    const float* __restrict__ Carry,
                                                    float* __restrict__ Out)
{
    const int c = blockIdx.x, b = blockIdx.y;
    const int hb = threadIdx.x * 4;
    const size_t base0 = ((size_t)(b * (T_ / 4) + c * (TC / 4)) * N_ + hb) * 4;
    const size_t str = (size_t)N_ * 4;

    ushort8v L[TC];
#pragma unroll
    for (int qq = 0; qq < TC / 4; qq++) {
        const size_t bse = base0 + (size_t)qq * str;
        L[qq * 4 + 0] = *(const ushort8v*)(Kz + bse);
        L[qq * 4 + 1] = *(const ushort8v*)(Kz + bse + 8);
        L[qq * 4 + 2] = *(const ushort8v*)(Kh + bse);
        L[qq * 4 + 3] = *(const ushort8v*)(Kh + bse + 8);
    }

    float cy[4];
    {
        float4 c4 = *(const float4*)(Carry + ((size_t)(b * NC + c)) * H_ + hb);
        cy[0] = c4.x; cy[1] = c4.y; cy[2] = c4.z; cy[3] = c4.w;
    }
    size_t ob = ((size_t)(b * (T_ + 1) + c * TC + 1)) * H_ + hb;
#pragma unroll
    for (int qq = 0; qq < TC / 4; qq++) {
        QUAD_MATH(L[qq * 4 + 0], L[qq * 4 + 1], L[qq * 4 + 2], L[qq * 4 + 3], {
            cy[j] = f * cy[j] + v;
            if (j == 3) { *(float4*)(Out + ob) = make_float4(cy[0], cy[1], cy[2], cy[3]); ob += H_; }
        })
    }
}

extern "C" void kernel_launch(void* const* d_in, const int* in_sizes, int n_in,
                              void* d_out, int out_size, void* d_ws, size_t ws_size,
                              hipStream_t stream)
{
    const float* x  = (const float*)d_in[0];
    const float* h0 = (const float*)d_in[1];
    const float* Wz = (const float*)d_in[2];
    const float* bz = (const float*)d_in[3];
    const float* Wh = (const float*)d_in[4];
    const float* bh = (const float*)d_in[5];
    float* out = (float*)d_out;

    char* ws = (char*)d_ws;
    unsigned short* xb  = (unsigned short*)ws; ws += (size_t)M_ * K_ * 2;   // 64 MiB
    unsigned short* wzb = (unsigned short*)ws; ws += (size_t)N_ * K_ * 2;   // 2 MiB
    unsigned short* whb = (unsigned short*)ws; ws += (size_t)N_ * K_ * 2;   // 2 MiB
    unsigned short* kz  = (unsigned short*)ws; ws += (size_t)M_ * N_ * 2;   // 64 MiB
    unsigned short* kh  = (unsigned short*)ws; ws += (size_t)M_ * N_ * 2;   // 64 MiB
    float* Fc    = (float*)ws; ws += (size_t)B_ * NC * H_ * 4;              // 8 MiB
    float* Vc    = (float*)ws; ws += (size_t)B_ * NC * H_ * 4;              // 8 MiB
    float* Carry = (float*)ws; ws += (size_t)B_ * NC * H_ * 4;              // 8 MiB

    cvt_kernel<<<2048, 256, 0, stream>>>(x, xb, M_ * K_ / 4);
    cvtw_kernel<<<dim3(128, 2), 256, 0, stream>>>(Wz, Wh, wzb, whb, N_ * K_ / 4);

    dim3 gg(M_ / 1024, N_ / 256, 2);
    gemm_kernel<<<gg, 512, 0, stream>>>(xb, wzb, whb, bz, bh, kz, kh);

    scanA_kernel<<<dim3(NC, B_), 256, 0, stream>>>(kz, kh, Fc, Vc);
    scanB_kernel<<<dim3(B_, H_ / 256), 64, 0, stream>>>(h0, Fc, Vc, Carry, out);
    scanC_kernel<<<dim3(NC, B_), 256, 0, stream>>>(kz, kh, Carry, out);
}

// Round 10
// 442.069 us; speedup vs baseline: 1.0535x; 1.0331x over previous
//
#include <hip/hip_runtime.h>
#include <stdint.h>

#define B_ 8
#define T_ 4096
#define D_ 1024
#define H_ 1024
#define M_ (B_*T_)   /* 32768 */
#define K_ D_
#define N_ H_
#define TC 32
#define NC (T_/TC)   /* 128 */

typedef short short8 __attribute__((ext_vector_type(8)));
typedef float f32x4 __attribute__((ext_vector_type(4)));
typedef unsigned short ushort8v __attribute__((ext_vector_type(8)));

__device__ __forceinline__ float bf2f(unsigned short u) {
    union { unsigned int i; float f; } x; x.i = ((unsigned int)u) << 16; return x.f;
}
__device__ __forceinline__ unsigned short f2bf(float f) {
    union { float f; unsigned int i; } x; x.f = f;
    unsigned int u = x.i;
    unsigned int r = u + 0x7fffu + ((u >> 16) & 1u);
    return (unsigned short)(r >> 16);
}
__device__ __forceinline__ void gld_lds16(const unsigned short* g, unsigned short* l) {
    __builtin_amdgcn_global_load_lds(
        (const __attribute__((address_space(1))) void*)(const void*)g,
        (__attribute__((address_space(3))) void*)(void*)l, 16, 0, 0);
}
// sigmoid/gfun via raw v_rcp_f32 (1 instr) instead of IEEE divide chain.
__device__ __forceinline__ float sigm_neg(float k) {   // 1/(1+exp(k)) = 1 - sigmoid(k)
    return __builtin_amdgcn_rcpf(1.f + __expf(k));
}
__device__ __forceinline__ float gfun(float x) {       // x>=0: x+0.5 ; x<0: sigmoid(x)
    float neg = __builtin_amdgcn_rcpf(1.f + __expf(-x));
    return x >= 0.f ? x + 0.5f : neg;
}

// ---------------- fp32 -> bf16 convert: x, Wz, Wh in ONE launch ----------------
__global__ void cvt_all(const float* __restrict__ x, const float* __restrict__ Wz,
                        const float* __restrict__ Wh,
                        unsigned short* __restrict__ xb, unsigned short* __restrict__ wzb,
                        unsigned short* __restrict__ whb) {
    const float* src;
    unsigned short* dst;
    int n4;
    if (blockIdx.y == 0)      { src = x;  dst = xb;  n4 = M_ * K_ / 4; }
    else if (blockIdx.y == 1) { src = Wz; dst = wzb; n4 = N_ * K_ / 4; }
    else                      { src = Wh; dst = whb; n4 = N_ * K_ / 4; }
    int i = blockIdx.x * blockDim.x + threadIdx.x;
    const int stride = gridDim.x * blockDim.x;
    for (; i < n4; i += stride) {
        float4 v = ((const float4*)src)[i];
        ushort4 o;
        o.x = f2bf(v.x); o.y = f2bf(v.y); o.z = f2bf(v.z); o.w = f2bf(v.w);
        ((ushort4*)dst)[i] = o;
    }
}

// ---------------- bf16 MFMA GEMM: 256x256 tile, 8-phase, persistent (steady state) -------
// PARKED at ~141 us / MfmaUtil 41%. The 128-AGPR accumulator leaves only 128 VGPRs at
// 8-wave residency (unified file, 256/wave), so the read-ahead pipeline cannot fit:
// R3 and R8 both spilled (WRITE_SIZE tripwire). Do not re-attempt without shrinking acc.
#define SB() __builtin_amdgcn_sched_barrier(0)
#define BAR() do { SB(); __builtin_amdgcn_s_barrier(); SB(); } while (0)

__global__ __launch_bounds__(512, 2) void gemm_kernel(
    const unsigned short* __restrict__ Xb,
    const unsigned short* __restrict__ Wzb,
    const unsigned short* __restrict__ Whb,
    const float* __restrict__ bz, const float* __restrict__ bh,
    unsigned short* __restrict__ KzOut, unsigned short* __restrict__ KhOut)
{
    __shared__ __align__(16) unsigned short ldsA[2][256 * 64];
    __shared__ __align__(16) unsigned short ldsB[2][256 * 64];

    const int bx = blockIdx.x;      // row-supertile: rows [bx*1024, bx*1024+1024)
    const int bn = blockIdx.y;
    const int mat = blockIdx.z;
    const unsigned short* Wb = mat ? Whb : Wzb;
    const float* bias = mat ? bh : bz;
    unsigned short* Out = mat ? KhOut : KzOut;

    const int tid = threadIdx.x;
    const int w = tid >> 6, lane = tid & 63;
    const int wm = w >> 2, wn = w & 3;       // 2 x 4 wave grid; wave owns 128x64 of C

    // ---- staging addressing (inverse-swizzled global source) ----
    const int srow = lane >> 3;                       // row within 8-row wave group
    const int schunk = ((lane & 7) ^ srow) << 3;      // ushort offset of 16B chunk
    const unsigned short* gA = Xb + (size_t)(bx * 1024 + srow) * K_ + schunk;
    const unsigned short* gB = Wb + (size_t)(bn * 256 + srow) * K_ + schunk;

// global K-step g: A row-block = (g>>4)*256 within the supertile, kt = g&15
#define STAGE_A(s, g, h) do { \
    gld_lds16(gA + (size_t)(((g) >> 4) * 256 + (h)*128 + w*8) * K_ + ((g)&15) * 64, \
              &ldsA[s][((h)*128 + w*8) * 64]); \
    gld_lds16(gA + (size_t)(((g) >> 4) * 256 + (h)*128 + 64 + w*8) * K_ + ((g)&15) * 64, \
              &ldsA[s][((h)*128 + 64 + w*8) * 64]); \
  } while (0)
#define STAGE_B(s, g, h) do { \
    gld_lds16(gB + (size_t)((h)*128 + w*8) * K_ + ((g)&15) * 64, \
              &ldsB[s][((h)*128 + w*8) * 64]); \
    gld_lds16(gB + (size_t)((h)*128 + 64 + w*8) * K_ + ((g)&15) * 64, \
              &ldsB[s][((h)*128 + 64 + w*8) * 64]); \
  } while (0)

    // ---- fragment read addressing (swizzled) ----
    const int lrow = lane & 15;
    const int q = lane >> 4;
    const int sw0 = (q ^ (lane & 7)) << 3;   // ushort offset of kh=0 slot; kh=1 is ^32

#define LDA(s, fm, kh) (*(const short8*)&ldsA[s][(wm*128 + (fm)*16 + lrow) * 64 + (sw0 ^ ((kh)*32))])
#define LDB(s, fn, kh) (*(const short8*)&ldsB[s][(wn*64  + (fn)*16 + lrow) * 64 + (sw0 ^ ((kh)*32))])

#define RD_A4(s, fmb) do { \
    _Pragma("unroll") for (int f = 0; f < 4; ++f) { Ar[f][0] = LDA(s, (fmb)+f, 0); Ar[f][1] = LDA(s, (fmb)+f, 1); } \
  } while (0)
#define RD_B2(s, fnb) do { \
    _Pragma("unroll") for (int g2_ = 0; g2_ < 2; ++g2_) { Br[(fnb)+g2_][0] = LDB(s, (fnb)+g2_, 0); Br[(fnb)+g2_][1] = LDB(s, (fnb)+g2_, 1); } \
  } while (0)

#define QUAD(mb, nb) do { \
    __builtin_amdgcn_s_setprio(1); \
    _Pragma("unroll") for (int f = 0; f < 4; ++f) { \
      _Pragma("unroll") for (int g2_ = 0; g2_ < 2; ++g2_) { \
        acc[(mb)+f][(nb)+g2_] = __builtin_amdgcn_mfma_f32_16x16x32_bf16(Ar[f][0], Br[(nb)+g2_][0], acc[(mb)+f][(nb)+g2_], 0, 0, 0); \
        acc[(mb)+f][(nb)+g2_] = __builtin_amdgcn_mfma_f32_16x16x32_bf16(Ar[f][1], Br[(nb)+g2_][1], acc[(mb)+f][(nb)+g2_], 0, 0, 0); \
      } \
    } \
    __builtin_amdgcn_s_setprio(0); \
  } while (0)

    f32x4 acc[8][4];
    short8 Ar[4][2], Br[4][2];

    // bias values are t-invariant; hoist
    float bb[4];
#pragma unroll
    for (int fn = 0; fn < 4; ++fn) bb[fn] = bias[bn * 256 + wn * 64 + fn * 16 + lrow];

    // ---- prologue: g=0 (slot0, A+B all halves) + g=1 B halves ----
    STAGE_B(0, 0, 0); STAGE_B(0, 0, 1);
    STAGE_A(0, 0, 0); STAGE_A(0, 0, 1);
    STAGE_B(1, 1, 0); STAGE_B(1, 1, 1);
    SB();
    asm volatile("s_waitcnt vmcnt(4)" ::: "memory");   // g=0 landed; g=1 B in flight
    BAR();

#pragma unroll 1
    for (int t = 0; t < 4; ++t) {
#pragma unroll
        for (int i = 0; i < 8; ++i)
#pragma unroll
            for (int j = 0; j < 4; ++j) acc[i][j] = (f32x4){0.f, 0.f, 0.f, 0.f};

#pragma unroll 1
        for (int i = 0; i < 8; ++i) {
            const int g1 = t * 16 + 2 * i + 1;
            const int g2 = g1 + 1;
            const int g3 = g1 + 2;
            const bool st = (g2 < 64);   // false only at t=3,i=7

            // ---- P1: read slot0 A(m0-3)+B(n0-1); stage slot1 A-h0 (g1) ----
            RD_A4(0, 0); RD_B2(0, 0);
            STAGE_A(1, g1, 0);
            BAR();
            QUAD(0, 0);
            BAR();
            // ---- P2: read slot0 B(n2-3); stage slot1 A-h1 (g1) ----
            RD_B2(0, 2);
            STAGE_A(1, g1, 1);
            BAR();
            QUAD(0, 2);
            BAR();
            // ---- P3: read slot0 A(m4-7); stage slot0 B-h0 (g2) ----
            RD_A4(0, 4);
            if (st) STAGE_B(0, g2, 0);
            BAR();
            QUAD(4, 0);
            BAR();
            // ---- P4: stage slot0 B-h1 (g2); GATE: g1 landed before P5 ----
            if (st) {
                STAGE_B(0, g2, 1);
                SB();
                asm volatile("s_waitcnt vmcnt(4)" ::: "memory");
            } else {
                asm volatile("s_waitcnt vmcnt(0)" ::: "memory");   // final drain
            }
            BAR();
            QUAD(4, 2);
            BAR();
            // ---- P5: read slot1 A(m0-3)+B(n0-1); stage slot0 A-h0 (g2) ----
            RD_A4(1, 0); RD_B2(1, 0);
            if (st) STAGE_A(0, g2, 0);
            BAR();
            QUAD(0, 0);
            BAR();
            // ---- P6: read slot1 B(n2-3); stage slot0 A-h1 (g2) ----
            RD_B2(1, 2);
            if (st) STAGE_A(0, g2, 1);
            BAR();
            QUAD(0, 2);
            BAR();
            // ---- P7: read slot1 A(m4-7); stage slot1 B-h0 (g3) ----
            RD_A4(1, 4);
            if (st) STAGE_B(1, g3, 0);
            BAR();
            QUAD(4, 0);
            BAR();
            // ---- P8: stage slot1 B-h1 (g3); GATE: g2 (slot0) landed before next P1 ----
            if (st) {
                STAGE_B(1, g3, 1);
                SB();
                asm volatile("s_waitcnt vmcnt(4)" ::: "memory");
            }
            BAR();
            QUAD(4, 2);
            BAR();
        }

        // ---- per-tile epilogue (no LDS, runs under in-flight prefetch) ----
        // K[m][n] at ((m>>2)*N + n)*4 + (m&3); m = (bx*4+t)*256 + wm*128 + fm*16 + q*4 + r
#pragma unroll
        for (int fn = 0; fn < 4; ++fn) {
            const int n = bn * 256 + wn * 64 + fn * 16 + lrow;
#pragma unroll
            for (int fm = 0; fm < 8; ++fm) {
                const int mq = (bx * 4 + t) * 64 + wm * 32 + fm * 4 + q;
                ushort4 o;
                o.x = f2bf(acc[fm][fn][0] + bb[fn]);
                o.y = f2bf(acc[fm][fn][1] + bb[fn]);
                o.z = f2bf(acc[fm][fn][2] + bb[fn]);
                o.w = f2bf(acc[fm][fn][3] + bb[fn]);
                *(ushort4*)(Out + ((size_t)mq * N_ + n) * 4) = o;
            }
        }
    }
}

// Packed-layout accessor note for scans:
// K[m][n] lives at ((m>>2)*N + n)*4 + (m&3), m = b*T + t.
// A thread owning columns hb..hb+3 loads, per t-quad q, two 16B vectors:
//   base = ((b*1024 + (t0>>2))*N + hb)*4 ; v0 = cols hb,hb+1 ; v1 = cols hb+2,hb+3
//   value(col j, t0+r) = v[j>>1][(j&1)*4 + r]

// per-t-quad math, shared by scanA/scanC
#define QUAD_MATH(Z0, Z1, HH0, HH1, CYSTMT)                                            \
    _Pragma("unroll")                                                                  \
    for (int r = 0; r < 4; r++) {                                                      \
        float kzf[4] = {bf2f(Z0[r]), bf2f(Z0[4 + r]), bf2f(Z1[r]), bf2f(Z1[4 + r])};   \
        float khf[4] = {bf2f(HH0[r]), bf2f(HH0[4 + r]), bf2f(HH1[r]), bf2f(HH1[4 + r])};\
        _Pragma("unroll")                                                              \
        for (int j = 0; j < 4; j++) {                                                  \
            float f = sigm_neg(kzf[j]);            /* 1 - sigmoid(kz) */               \
            float v = (1.f - f) * gfun(khf[j]);    /* sigmoid(kz)*g(kh) */             \
            CYSTMT                                                                     \
        }                                                                              \
    }

// ---------------- scan A: per-chunk affine aggregates (F = prod f, V) ----------------
// 2-deep register prefetch (best-measured variant, R5)
__global__ __launch_bounds__(256) void scanA_kernel(const unsigned short* __restrict__ Kz,
                                                    const unsigned short* __restrict__ Kh,
                                                    float* __restrict__ Fc, float* __restrict__ Vc)
{
    const int c = blockIdx.x, b = blockIdx.y;
    const int hb = threadIdx.x * 4;
    float F[4] = {1.f, 1.f, 1.f, 1.f}, V[4] = {0.f, 0.f, 0.f, 0.f};
    const size_t base0 = ((size_t)(b * (T_ / 4) + c * (TC / 4)) * N_ + hb) * 4;
    const size_t str = (size_t)N_ * 4;
    ushort8v cz0 = *(const ushort8v*)(Kz + base0);
    ushort8v cz1 = *(const ushort8v*)(Kz + base0 + 8);
    ushort8v ch0 = *(const ushort8v*)(Kh + base0);
    ushort8v ch1 = *(const ushort8v*)(Kh + base0 + 8);
    ushort8v az0 = *(const ushort8v*)(Kz + base0 + str);
    ushort8v az1 = *(const ushort8v*)(Kz + base0 + str + 8);
    ushort8v ah0 = *(const ushort8v*)(Kh + base0 + str);
    ushort8v ah1 = *(const ushort8v*)(Kh + base0 + str + 8);
#pragma unroll 1
    for (int qq = 0; qq < TC / 4; qq++) {
        const int qn = (qq + 2 < TC / 4) ? qq + 2 : TC / 4 - 1;   // clamped tail (L1-hot)
        const size_t nb = base0 + (size_t)qn * str;
        ushort8v bz0 = *(const ushort8v*)(Kz + nb);
        ushort8v bz1 = *(const ushort8v*)(Kz + nb + 8);
        ushort8v bh0 = *(const ushort8v*)(Kh + nb);
        ushort8v bh1 = *(const ushort8v*)(Kh + nb + 8);
        QUAD_MATH(cz0, cz1, ch0, ch1, { V[j] = f * V[j] + v; F[j] *= f; })
        cz0 = az0; cz1 = az1; ch0 = ah0; ch1 = ah1;
        az0 = bz0; az1 = bz1; ah0 = bh0; ah1 = bh1;
    }
    size_t o = ((size_t)(b * NC + c)) * H_ + hb;
    *(float4*)(Fc + o) = make_float4(F[0], F[1], F[2], F[3]);
    *(float4*)(Vc + o) = make_float4(V[0], V[1], V[2], V[3]);
}

// ---------------- scan C: self-carry + replay (scanB folded in) ----------------
// Each block (b,c) computes its own carry by scanning the L2-hot Fc/Vc prefix
// [0, c) with 8-wide batched prefetch (loads independent; only the FMA chain is
// serial: ~16 batches x ~350cy = ~2.4us worst block). Removes the scanB dispatch,
// two graph dependencies, and the Carry buffer round-trip.
__global__ __launch_bounds__(256) void scanC_kernel(const unsigned short* __restrict__ Kz,
                                                    const unsigned short* __restrict__ Kh,
                                                    const float* __restrict__ Fc,
                                                    const float* __restrict__ Vc,
                                                    const float* __restrict__ h0,
                                                    float* __restrict__ Out)
{
    const int c = blockIdx.x, b = blockIdx.y;
    const int hb = threadIdx.x * 4;

    // ---- carry from h0 through chunks [0, c) ----
    float cy[4];
#pragma unroll
    for (int k = 0; k < 4; ++k) cy[k] = gfun(h0[(size_t)b * H_ + hb + k]);
    if (c == 0) {
        *(float4*)(Out + (size_t)b * (T_ + 1) * H_ + hb) =
            make_float4(cy[0], cy[1], cy[2], cy[3]);
    }
    {
        size_t o = ((size_t)(b * NC)) * H_ + hb;
        int j = 0;
        while (j < c) {
            const int bnc = (c - j < 8) ? (c - j) : 8;
            float4 Fb[8], Vb[8];
#pragma unroll
            for (int k = 0; k < 8; ++k) {
                if (k < bnc) {
                    Fb[k] = *(const float4*)(Fc + o + (size_t)k * H_);
                    Vb[k] = *(const float4*)(Vc + o + (size_t)k * H_);
                }
            }
#pragma unroll
            for (int k = 0; k < 8; ++k) {
                if (k < bnc) {
                    cy[0] = Fb[k].x * cy[0] + Vb[k].x;
                    cy[1] = Fb[k].y * cy[1] + Vb[k].y;
                    cy[2] = Fb[k].z * cy[2] + Vb[k].z;
                    cy[3] = Fb[k].w * cy[3] + Vb[k].w;
                }
            }
            o += (size_t)bnc * H_;
            j += bnc;
        }
    }

    // ---- replay chunk with carry (2-deep prefetch) ----
    const size_t base0 = ((size_t)(b * (T_ / 4) + c * (TC / 4)) * N_ + hb) * 4;
    const size_t str = (size_t)N_ * 4;
    size_t ob = ((size_t)(b * (T_ + 1) + c * TC + 1)) * H_ + hb;
    ushort8v cz0 = *(const ushort8v*)(Kz + base0);
    ushort8v cz1 = *(const ushort8v*)(Kz + base0 + 8);
    ushort8v ch0 = *(const ushort8v*)(Kh + base0);
    ushort8v ch1 = *(const ushort8v*)(Kh + base0 + 8);
    ushort8v az0 = *(const ushort8v*)(Kz + base0 + str);
    ushort8v az1 = *(const ushort8v*)(Kz + base0 + str + 8);
    ushort8v ah0 = *(const ushort8v*)(Kh + base0 + str);
    ushort8v ah1 = *(const ushort8v*)(Kh + base0 + str + 8);
#pragma unroll 1
    for (int qq = 0; qq < TC / 4; qq++) {
        const int qn = (qq + 2 < TC / 4) ? qq + 2 : TC / 4 - 1;
        const size_t nb = base0 + (size_t)qn * str;
        ushort8v bz0 = *(const ushort8v*)(Kz + nb);
        ushort8v bz1 = *(const ushort8v*)(Kz + nb + 8);
        ushort8v bh0 = *(const ushort8v*)(Kh + nb);
        ushort8v bh1 = *(const ushort8v*)(Kh + nb + 8);
        QUAD_MATH(cz0, cz1, ch0, ch1, {
            cy[j] = f * cy[j] + v;
            if (j == 3) { *(float4*)(Out + ob) = make_float4(cy[0], cy[1], cy[2], cy[3]); ob += H_; }
        })
        cz0 = az0; cz1 = az1; ch0 = ah0; ch1 = ah1;
        az0 = bz0; az1 = bz1; ah0 = bh0; ah1 = bh1;
    }
}

extern "C" void kernel_launch(void* const* d_in, const int* in_sizes, int n_in,
                              void* d_out, int out_size, void* d_ws, size_t ws_size,
                              hipStream_t stream)
{
    const float* x  = (const float*)d_in[0];
    const float* h0 = (const float*)d_in[1];
    const float* Wz = (const float*)d_in[2];
    const float* bz = (const float*)d_in[3];
    const float* Wh = (const float*)d_in[4];
    const float* bh = (const float*)d_in[5];
    float* out = (float*)d_out;

    char* ws = (char*)d_ws;
    unsigned short* xb  = (unsigned short*)ws; ws += (size_t)M_ * K_ * 2;   // 64 MiB
    unsigned short* wzb = (unsigned short*)ws; ws += (size_t)N_ * K_ * 2;   // 2 MiB
    unsigned short* whb = (unsigned short*)ws; ws += (size_t)N_ * K_ * 2;   // 2 MiB
    unsigned short* kz  = (unsigned short*)ws; ws += (size_t)M_ * N_ * 2;   // 64 MiB
    unsigned short* kh  = (unsigned short*)ws; ws += (size_t)M_ * N_ * 2;   // 64 MiB
    float* Fc    = (float*)ws; ws += (size_t)B_ * NC * H_ * 4;              // 4 MiB
    float* Vc    = (float*)ws; ws += (size_t)B_ * NC * H_ * 4;              // 4 MiB

    cvt_all<<<dim3(2048, 3), 256, 0, stream>>>(x, Wz, Wh, xb, wzb, whb);

    dim3 gg(M_ / 1024, N_ / 256, 2);
    gemm_kernel<<<gg, 512, 0, stream>>>(xb, wzb, whb, bz, bh, kz, kh);

    scanA_kernel<<<dim3(NC, B_), 256, 0, stream>>>(kz, kh, Fc, Vc);
    scanC_kernel<<<dim3(NC, B_), 256, 0, stream>>>(kz, kh, Fc, Vc, h0, out);
}

// Round 12
// 417.499 us; speedup vs baseline: 1.1155x; 1.0589x over previous
//
#include <hip/hip_runtime.h>
#include <stdint.h>

#define B_ 8
#define T_ 4096
#define D_ 1024
#define H_ 1024
#define M_ (B_*T_)   /* 32768 */
#define K_ D_
#define N_ H_
#define TC 32
#define NC (T_/TC)   /* 128 */

typedef short short8 __attribute__((ext_vector_type(8)));
typedef float f32x4 __attribute__((ext_vector_type(4)));
typedef unsigned short ushort8v __attribute__((ext_vector_type(8)));

__device__ __forceinline__ float bf2f(unsigned short u) {
    union { unsigned int i; float f; } x; x.i = ((unsigned int)u) << 16; return x.f;
}
__device__ __forceinline__ unsigned short f2bf(float f) {
    union { float f; unsigned int i; } x; x.f = f;
    unsigned int u = x.i;
    unsigned int r = u + 0x7fffu + ((u >> 16) & 1u);
    return (unsigned short)(r >> 16);
}
__device__ __forceinline__ void gld_lds16(const unsigned short* g, unsigned short* l) {
    __builtin_amdgcn_global_load_lds(
        (const __attribute__((address_space(1))) void*)(const void*)g,
        (__attribute__((address_space(3))) void*)(void*)l, 16, 0, 0);
}
// sigmoid/gfun via raw v_rcp_f32 (1 instr) instead of IEEE divide chain.
__device__ __forceinline__ float sigm_neg(float k) {   // 1/(1+exp(k)) = 1 - sigmoid(k)
    return __builtin_amdgcn_rcpf(1.f + __expf(k));
}
__device__ __forceinline__ float gfun(float x) {       // x>=0: x+0.5 ; x<0: sigmoid(x)
    float neg = __builtin_amdgcn_rcpf(1.f + __expf(-x));
    return x >= 0.f ? x + 0.5f : neg;
}
// nontemporal helpers: builtin requires ext-vector types, not HIP_vector_type
__device__ __forceinline__ f32x4 nt_load_f4(const float* p) {
    return __builtin_nontemporal_load(reinterpret_cast<const f32x4*>(p));
}
__device__ __forceinline__ void nt_store_f4(float* p, float a, float b, float c, float d) {
    f32x4 v = {a, b, c, d};
    __builtin_nontemporal_store(v, reinterpret_cast<f32x4*>(p));
}

// ---------------- fp32 -> bf16 convert: x, Wz, Wh in ONE launch ----------------
// x is read-once: nontemporal loads keep it from polluting L3 (which must hold kz/kh
// later). xb store stays cached (gemm re-reads it).
__global__ void cvt_all(const float* __restrict__ x, const float* __restrict__ Wz,
                        const float* __restrict__ Wh,
                        unsigned short* __restrict__ xb, unsigned short* __restrict__ wzb,
                        unsigned short* __restrict__ whb) {
    const float* src;
    unsigned short* dst;
    int n4;
    if (blockIdx.y == 0)      { src = x;  dst = xb;  n4 = M_ * K_ / 4; }
    else if (blockIdx.y == 1) { src = Wz; dst = wzb; n4 = N_ * K_ / 4; }
    else                      { src = Wh; dst = whb; n4 = N_ * K_ / 4; }
    int i = blockIdx.x * blockDim.x + threadIdx.x;
    const int stride = gridDim.x * blockDim.x;
    for (; i < n4; i += stride) {
        f32x4 v = nt_load_f4(src + (size_t)i * 4);
        ushort4 o;
        o.x = f2bf(v.x); o.y = f2bf(v.y); o.z = f2bf(v.z); o.w = f2bf(v.w);
        ((ushort4*)dst)[i] = o;
    }
}

// ---------------- bf16 MFMA GEMM: 256x256 tile, 8-phase, persistent (steady state) -------
// PARKED at ~141 us / MfmaUtil 41%. The 128-AGPR accumulator leaves only 128 VGPRs at
// 8-wave residency (unified file, 256/wave), so the read-ahead pipeline cannot fit:
// R3 and R8 both spilled (WRITE_SIZE tripwire). Do not re-attempt without shrinking acc.
#define SB() __builtin_amdgcn_sched_barrier(0)
#define BAR() do { SB(); __builtin_amdgcn_s_barrier(); SB(); } while (0)

__global__ __launch_bounds__(512, 2) void gemm_kernel(
    const unsigned short* __restrict__ Xb,
    const unsigned short* __restrict__ Wzb,
    const unsigned short* __restrict__ Whb,
    const float* __restrict__ bz, const float* __restrict__ bh,
    unsigned short* __restrict__ KzOut, unsigned short* __restrict__ KhOut)
{
    __shared__ __align__(16) unsigned short ldsA[2][256 * 64];
    __shared__ __align__(16) unsigned short ldsB[2][256 * 64];

    const int bx = blockIdx.x;      // row-supertile: rows [bx*1024, bx*1024+1024)
    const int bn = blockIdx.y;
    const int mat = blockIdx.z;
    const unsigned short* Wb = mat ? Whb : Wzb;
    const float* bias = mat ? bh : bz;
    unsigned short* Out = mat ? KhOut : KzOut;

    const int tid = threadIdx.x;
    const int w = tid >> 6, lane = tid & 63;
    const int wm = w >> 2, wn = w & 3;       // 2 x 4 wave grid; wave owns 128x64 of C

    // ---- staging addressing (inverse-swizzled global source) ----
    const int srow = lane >> 3;                       // row within 8-row wave group
    const int schunk = ((lane & 7) ^ srow) << 3;      // ushort offset of 16B chunk
    const unsigned short* gA = Xb + (size_t)(bx * 1024 + srow) * K_ + schunk;
    const unsigned short* gB = Wb + (size_t)(bn * 256 + srow) * K_ + schunk;

// global K-step g: A row-block = (g>>4)*256 within the supertile, kt = g&15
#define STAGE_A(s, g, h) do { \
    gld_lds16(gA + (size_t)(((g) >> 4) * 256 + (h)*128 + w*8) * K_ + ((g)&15) * 64, \
              &ldsA[s][((h)*128 + w*8) * 64]); \
    gld_lds16(gA + (size_t)(((g) >> 4) * 256 + (h)*128 + 64 + w*8) * K_ + ((g)&15) * 64, \
              &ldsA[s][((h)*128 + 64 + w*8) * 64]); \
  } while (0)
#define STAGE_B(s, g, h) do { \
    gld_lds16(gB + (size_t)((h)*128 + w*8) * K_ + ((g)&15) * 64, \
              &ldsB[s][((h)*128 + w*8) * 64]); \
    gld_lds16(gB + (size_t)((h)*128 + 64 + w*8) * K_ + ((g)&15) * 64, \
              &ldsB[s][((h)*128 + 64 + w*8) * 64]); \
  } while (0)

    // ---- fragment read addressing (swizzled) ----
    const int lrow = lane & 15;
    const int q = lane >> 4;
    const int sw0 = (q ^ (lane & 7)) << 3;   // ushort offset of kh=0 slot; kh=1 is ^32

#define LDA(s, fm, kh) (*(const short8*)&ldsA[s][(wm*128 + (fm)*16 + lrow) * 64 + (sw0 ^ ((kh)*32))])
#define LDB(s, fn, kh) (*(const short8*)&ldsB[s][(wn*64  + (fn)*16 + lrow) * 64 + (sw0 ^ ((kh)*32))])

#define RD_A4(s, fmb) do { \
    _Pragma("unroll") for (int f = 0; f < 4; ++f) { Ar[f][0] = LDA(s, (fmb)+f, 0); Ar[f][1] = LDA(s, (fmb)+f, 1); } \
  } while (0)
#define RD_B2(s, fnb) do { \
    _Pragma("unroll") for (int g2_ = 0; g2_ < 2; ++g2_) { Br[(fnb)+g2_][0] = LDB(s, (fnb)+g2_, 0); Br[(fnb)+g2_][1] = LDB(s, (fnb)+g2_, 1); } \
  } while (0)

#define QUAD(mb, nb) do { \
    __builtin_amdgcn_s_setprio(1); \
    _Pragma("unroll") for (int f = 0; f < 4; ++f) { \
      _Pragma("unroll") for (int g2_ = 0; g2_ < 2; ++g2_) { \
        acc[(mb)+f][(nb)+g2_] = __builtin_amdgcn_mfma_f32_16x16x32_bf16(Ar[f][0], Br[(nb)+g2_][0], acc[(mb)+f][(nb)+g2_], 0, 0, 0); \
        acc[(mb)+f][(nb)+g2_] = __builtin_amdgcn_mfma_f32_16x16x32_bf16(Ar[f][1], Br[(nb)+g2_][1], acc[(mb)+f][(nb)+g2_], 0, 0, 0); \
      } \
    } \
    __builtin_amdgcn_s_setprio(0); \
  } while (0)

    f32x4 acc[8][4];
    short8 Ar[4][2], Br[4][2];

    // bias values are t-invariant; hoist
    float bb[4];
#pragma unroll
    for (int fn = 0; fn < 4; ++fn) bb[fn] = bias[bn * 256 + wn * 64 + fn * 16 + lrow];

    // ---- prologue: g=0 (slot0, A+B all halves) + g=1 B halves ----
    STAGE_B(0, 0, 0); STAGE_B(0, 0, 1);
    STAGE_A(0, 0, 0); STAGE_A(0, 0, 1);
    STAGE_B(1, 1, 0); STAGE_B(1, 1, 1);
    SB();
    asm volatile("s_waitcnt vmcnt(4)" ::: "memory");   // g=0 landed; g=1 B in flight
    BAR();

#pragma unroll 1
    for (int t = 0; t < 4; ++t) {
#pragma unroll
        for (int i = 0; i < 8; ++i)
#pragma unroll
            for (int j = 0; j < 4; ++j) acc[i][j] = (f32x4){0.f, 0.f, 0.f, 0.f};

#pragma unroll 1
        for (int i = 0; i < 8; ++i) {
            const int g1 = t * 16 + 2 * i + 1;
            const int g2 = g1 + 1;
            const int g3 = g1 + 2;
            const bool st = (g2 < 64);   // false only at t=3,i=7

            // ---- P1: read slot0 A(m0-3)+B(n0-1); stage slot1 A-h0 (g1) ----
            RD_A4(0, 0); RD_B2(0, 0);
            STAGE_A(1, g1, 0);
            BAR();
            QUAD(0, 0);
            BAR();
            // ---- P2: read slot0 B(n2-3); stage slot1 A-h1 (g1) ----
            RD_B2(0, 2);
            STAGE_A(1, g1, 1);
            BAR();
            QUAD(0, 2);
            BAR();
            // ---- P3: read slot0 A(m4-7); stage slot0 B-h0 (g2) ----
            RD_A4(0, 4);
            if (st) STAGE_B(0, g2, 0);
            BAR();
            QUAD(4, 0);
            BAR();
            // ---- P4: stage slot0 B-h1 (g2); GATE: g1 landed before P5 ----
            if (st) {
                STAGE_B(0, g2, 1);
                SB();
                asm volatile("s_waitcnt vmcnt(4)" ::: "memory");
            } else {
                asm volatile("s_waitcnt vmcnt(0)" ::: "memory");   // final drain
            }
            BAR();
            QUAD(4, 2);
            BAR();
            // ---- P5: read slot1 A(m0-3)+B(n0-1); stage slot0 A-h0 (g2) ----
            RD_A4(1, 0); RD_B2(1, 0);
            if (st) STAGE_A(0, g2, 0);
            BAR();
            QUAD(0, 0);
            BAR();
            // ---- P6: read slot1 B(n2-3); stage slot0 A-h1 (g2) ----
            RD_B2(1, 2);
            if (st) STAGE_A(0, g2, 1);
            BAR();
            QUAD(0, 2);
            BAR();
            // ---- P7: read slot1 A(m4-7); stage slot1 B-h0 (g3) ----
            RD_A4(1, 4);
            if (st) STAGE_B(1, g3, 0);
            BAR();
            QUAD(4, 0);
            BAR();
            // ---- P8: stage slot1 B-h1 (g3); GATE: g2 (slot0) landed before next P1 ----
            if (st) {
                STAGE_B(1, g3, 1);
                SB();
                asm volatile("s_waitcnt vmcnt(4)" ::: "memory");
            }
            BAR();
            QUAD(4, 2);
            BAR();
        }

        // ---- per-tile epilogue (no LDS, runs under in-flight prefetch) ----
        // K[m][n] at ((m>>2)*N + n)*4 + (m&3); m = (bx*4+t)*256 + wm*128 + fm*16 + q*4 + r
        // K writes stay CACHED: scanA/scanC read them from L3.
#pragma unroll
        for (int fn = 0; fn < 4; ++fn) {
            const int n = bn * 256 + wn * 64 + fn * 16 + lrow;
#pragma unroll
            for (int fm = 0; fm < 8; ++fm) {
                const int mq = (bx * 4 + t) * 64 + wm * 32 + fm * 4 + q;
                ushort4 o;
                o.x = f2bf(acc[fm][fn][0] + bb[fn]);
                o.y = f2bf(acc[fm][fn][1] + bb[fn]);
                o.z = f2bf(acc[fm][fn][2] + bb[fn]);
                o.w = f2bf(acc[fm][fn][3] + bb[fn]);
                *(ushort4*)(Out + ((size_t)mq * N_ + n) * 4) = o;
            }
        }
    }
}

// Packed-layout accessor note for scans:
// K[m][n] lives at ((m>>2)*N + n)*4 + (m&3), m = b*T + t.
// A thread owning columns hb..hb+3 loads, per t-quad q, two 16B vectors:
//   base = ((b*1024 + (t0>>2))*N + hb)*4 ; v0 = cols hb,hb+1 ; v1 = cols hb+2,hb+3
//   value(col j, t0+r) = v[j>>1][(j&1)*4 + r]

// per-t-quad math, shared by scanA/scanC
#define QUAD_MATH(Z0, Z1, HH0, HH1, CYSTMT)                                            \
    _Pragma("unroll")                                                                  \
    for (int r = 0; r < 4; r++) {                                                      \
        float kzf[4] = {bf2f(Z0[r]), bf2f(Z0[4 + r]), bf2f(Z1[r]), bf2f(Z1[4 + r])};   \
        float khf[4] = {bf2f(HH0[r]), bf2f(HH0[4 + r]), bf2f(HH1[r]), bf2f(HH1[4 + r])};\
        _Pragma("unroll")                                                              \
        for (int j = 0; j < 4; j++) {                                                  \
            float f = sigm_neg(kzf[j]);            /* 1 - sigmoid(kz) */               \
            float v = (1.f - f) * gfun(khf[j]);    /* sigmoid(kz)*g(kh) */             \
            CYSTMT                                                                     \
        }                                                                              \
    }

// ---------------- scan A: per-chunk affine aggregates (F = prod f, V) ----------------
// 2-deep register prefetch (best-measured variant, R5)
__global__ __launch_bounds__(256) void scanA_kernel(const unsigned short* __restrict__ Kz,
                                                    const unsigned short* __restrict__ Kh,
                                                    float* __restrict__ Fc, float* __restrict__ Vc)
{
    const int c = blockIdx.x, b = blockIdx.y;
    const int hb = threadIdx.x * 4;
    float F[4] = {1.f, 1.f, 1.f, 1.f}, V[4] = {0.f, 0.f, 0.f, 0.f};
    const size_t base0 = ((size_t)(b * (T_ / 4) + c * (TC / 4)) * N_ + hb) * 4;
    const size_t str = (size_t)N_ * 4;
    ushort8v cz0 = *(const ushort8v*)(Kz + base0);
    ushort8v cz1 = *(const ushort8v*)(Kz + base0 + 8);
    ushort8v ch0 = *(const ushort8v*)(Kh + base0);
    ushort8v ch1 = *(const ushort8v*)(Kh + base0 + 8);
    ushort8v az0 = *(const ushort8v*)(Kz + base0 + str);
    ushort8v az1 = *(const ushort8v*)(Kz + base0 + str + 8);
    ushort8v ah0 = *(const ushort8v*)(Kh + base0 + str);
    ushort8v ah1 = *(const ushort8v*)(Kh + base0 + str + 8);
#pragma unroll 1
    for (int qq = 0; qq < TC / 4; qq++) {
        const int qn = (qq + 2 < TC / 4) ? qq + 2 : TC / 4 - 1;   // clamped tail (L1-hot)
        const size_t nb = base0 + (size_t)qn * str;
        ushort8v bz0 = *(const ushort8v*)(Kz + nb);
        ushort8v bz1 = *(const ushort8v*)(Kz + nb + 8);
        ushort8v bh0 = *(const ushort8v*)(Kh + nb);
        ushort8v bh1 = *(const ushort8v*)(Kh + nb + 8);
        QUAD_MATH(cz0, cz1, ch0, ch1, { V[j] = f * V[j] + v; F[j] *= f; })
        cz0 = az0; cz1 = az1; ch0 = ah0; ch1 = ah1;
        az0 = bz0; az1 = bz1; ah0 = bh0; ah1 = bh1;
    }
    size_t o = ((size_t)(b * NC + c)) * H_ + hb;
    *(float4*)(Fc + o) = make_float4(F[0], F[1], F[2], F[3]);
    *(float4*)(Vc + o) = make_float4(V[0], V[1], V[2], V[3]);
}

// ---------------- scan C: self-carry + replay (scanB folded in) ----------------
// Out is write-once/never-read: NONTEMPORAL stores keep the 134 MB of Out from
// evicting the L3-resident kz/kh this kernel is still reading (the theory: scanC's
// own writes were turning its later reads into HBM misses).
__global__ __launch_bounds__(256) void scanC_kernel(const unsigned short* __restrict__ Kz,
                                                    const unsigned short* __restrict__ Kh,
                                                    const float* __restrict__ Fc,
                                                    const float* __restrict__ Vc,
                                                    const float* __restrict__ h0,
                                                    float* __restrict__ Out)
{
    const int c = blockIdx.x, b = blockIdx.y;
    const int hb = threadIdx.x * 4;

    // ---- carry from h0 through chunks [0, c) ----
    float cy[4];
#pragma unroll
    for (int k = 0; k < 4; ++k) cy[k] = gfun(h0[(size_t)b * H_ + hb + k]);
    if (c == 0) {
        nt_store_f4(Out + (size_t)b * (T_ + 1) * H_ + hb, cy[0], cy[1], cy[2], cy[3]);
    }
    {
        size_t o = ((size_t)(b * NC)) * H_ + hb;
        int j = 0;
        while (j < c) {
            const int bnc = (c - j < 8) ? (c - j) : 8;
            float4 Fb[8], Vb[8];
#pragma unroll
            for (int k = 0; k < 8; ++k) {
                if (k < bnc) {
                    Fb[k] = *(const float4*)(Fc + o + (size_t)k * H_);
                    Vb[k] = *(const float4*)(Vc + o + (size_t)k * H_);
                }
            }
#pragma unroll
            for (int k = 0; k < 8; ++k) {
                if (k < bnc) {
                    cy[0] = Fb[k].x * cy[0] + Vb[k].x;
                    cy[1] = Fb[k].y * cy[1] + Vb[k].y;
                    cy[2] = Fb[k].z * cy[2] + Vb[k].z;
                    cy[3] = Fb[k].w * cy[3] + Vb[k].w;
                }
            }
            o += (size_t)bnc * H_;
            j += bnc;
        }
    }

    // ---- replay chunk with carry (2-deep prefetch, NT output stores) ----
    const size_t base0 = ((size_t)(b * (T_ / 4) + c * (TC / 4)) * N_ + hb) * 4;
    const size_t str = (size_t)N_ * 4;
    size_t ob = ((size_t)(b * (T_ + 1) + c * TC + 1)) * H_ + hb;
    ushort8v cz0 = *(const ushort8v*)(Kz + base0);
    ushort8v cz1 = *(const ushort8v*)(Kz + base0 + 8);
    ushort8v ch0 = *(const ushort8v*)(Kh + base0);
    ushort8v ch1 = *(const ushort8v*)(Kh + base0 + 8);
    ushort8v az0 = *(const ushort8v*)(Kz + base0 + str);
    ushort8v az1 = *(const ushort8v*)(Kz + base0 + str + 8);
    ushort8v ah0 = *(const ushort8v*)(Kh + base0 + str);
    ushort8v ah1 = *(const ushort8v*)(Kh + base0 + str + 8);
#pragma unroll 1
    for (int qq = 0; qq < TC / 4; qq++) {
        const int qn = (qq + 2 < TC / 4) ? qq + 2 : TC / 4 - 1;
        const size_t nb = base0 + (size_t)qn * str;
        ushort8v bz0 = *(const ushort8v*)(Kz + nb);
        ushort8v bz1 = *(const ushort8v*)(Kz + nb + 8);
        ushort8v bh0 = *(const ushort8v*)(Kh + nb);
        ushort8v bh1 = *(const ushort8v*)(Kh + nb + 8);
        QUAD_MATH(cz0, cz1, ch0, ch1, {
            cy[j] = f * cy[j] + v;
            if (j == 3) {
                nt_store_f4(Out + ob, cy[0], cy[1], cy[2], cy[3]);
                ob += H_;
            }
        })
        cz0 = az0; cz1 = az1; ch0 = ah0; ch1 = ah1;
        az0 = bz0; az1 = bz1; ah0 = bh0; ah1 = bh1;
    }
}

extern "C" void kernel_launch(void* const* d_in, const int* in_sizes, int n_in,
                              void* d_out, int out_size, void* d_ws, size_t ws_size,
                              hipStream_t stream)
{
    const float* x  = (const float*)d_in[0];
    const float* h0 = (const float*)d_in[1];
    const float* Wz = (const float*)d_in[2];
    const float* bz = (const float*)d_in[3];
    const float* Wh = (const float*)d_in[4];
    const float* bh = (const float*)d_in[5];
    float* out = (float*)d_out;

    char* ws = (char*)d_ws;
    unsigned short* xb  = (unsigned short*)ws; ws += (size_t)M_ * K_ * 2;   // 64 MiB
    unsigned short* wzb = (unsigned short*)ws; ws += (size_t)N_ * K_ * 2;   // 2 MiB
    unsigned short* whb = (unsigned short*)ws; ws += (size_t)N_ * K_ * 2;   // 2 MiB
    unsigned short* kz  = (unsigned short*)ws; ws += (size_t)M_ * N_ * 2;   // 64 MiB
    unsigned short* kh  = (unsigned short*)ws; ws += (size_t)M_ * N_ * 2;   // 64 MiB
    float* Fc    = (float*)ws; ws += (size_t)B_ * NC * H_ * 4;              // 4 MiB
    float* Vc    = (float*)ws; ws += (size_t)B_ * NC * H_ * 4;              // 4 MiB

    cvt_all<<<dim3(2048, 3), 256, 0, stream>>>(x, Wz, Wh, xb, wzb, whb);

    dim3 gg(M_ / 1024, N_ / 256, 2);
    gemm_kernel<<<gg, 512, 0, stream>>>(xb, wzb, whb, bz, bh, kz, kh);

    scanA_kernel<<<dim3(NC, B_), 256, 0, stream>>>(kz, kh, Fc, Vc);
    scanC_kernel<<<dim3(NC, B_), 256, 0, stream>>>(kz, kh, Fc, Vc, h0, out);
}